// Round 1
// 704.197 us; speedup vs baseline: 1.2594x; 1.2594x over previous
//
#include <hip/hip_runtime.h>

// LightGCN-style 3-layer bipartite propagation.
// R6: histo_kernel was the top dispatch (160us/iter, 124MB WRITE_SIZE =
// 4M device-scope atomicAdds punching through to HBM). Replaced the whole
// per-row histogram + 3-kernel scan pipeline with an atomic-free path:
//   msplit_hist (LDS bucket histos, kept) -> msplit_offsets (per-bucket
//   block-scan, now also emits bucket totals) -> scan_buckets (587-value
//   scan -> bucket CSR bases) -> msplit_scatter (kept, cursors = rel+base)
//   -> bucket_build (NEW: per-bucket 256-counter LDS histogram + LDS scan
//   builds ptr[] inline, then scatters with LDS cursors).
// Zero global atomics anywhere in the build. bf16 gather SpMM kept.

#define NUM_USERS 100000
#define NUM_ITEMS 50000
#define EMBED_DIM 128
#define NNZ_COUNT 2000000
#define NBUCK_U 391            // ceil(100000/256)
#define NBUCK_I 196            // ceil(50000/256)
#define EPB 8192               // edges per multisplit block
#define NBLK 245               // ceil(NNZ_COUNT/EPB)

// ---------------- bf16 helpers (manual RTNE) ----------------

__device__ __forceinline__ unsigned bf16_rnd(float f) {
    unsigned u = __float_as_uint(f);
    return (u + 0x7FFFu + ((u >> 16) & 1u)) >> 16;
}
__device__ __forceinline__ unsigned pack_bf16(float x, float y) {
    return bf16_rnd(x) | (bf16_rnd(y) << 16);
}

__global__ __launch_bounds__(256) void to_bf16_kernel(
    const float* __restrict__ a, unsigned* __restrict__ o, int n8)
{
    int i = blockIdx.x * 256 + threadIdx.x;
    if (i >= n8) return;
    const float4* a4 = reinterpret_cast<const float4*>(a);
    float4 x = a4[i * 2], y = a4[i * 2 + 1];
    uint4 r;
    r.x = pack_bf16(x.x, x.y); r.y = pack_bf16(x.z, x.w);
    r.z = pack_bf16(y.x, y.y); r.w = pack_bf16(y.z, y.w);
    reinterpret_cast<uint4*>(o)[i] = r;
}

// ---------------- LDS-aggregated multisplit (phase A) ----------------
// Zero global atomics: per-block LDS histogram -> per-(bucket,block) counts.

__global__ __launch_bounds__(256) void msplit_hist(
    const int* __restrict__ rows, const int* __restrict__ cols,
    int* __restrict__ hist_u, int* __restrict__ hist_i)
{
    __shared__ int h[NBUCK_U + NBUCK_I];
    for (int i = threadIdx.x; i < NBUCK_U + NBUCK_I; i += 256) h[i] = 0;
    __syncthreads();
    const int base = blockIdx.x * EPB;
    const int end = min(base + EPB, NNZ_COUNT);
    for (int e = base + threadIdx.x; e < end; e += 256) {
        atomicAdd(&h[rows[e] >> 8], 1);
        atomicAdd(&h[NBUCK_U + (cols[e] >> 8)], 1);
    }
    __syncthreads();
    for (int b = threadIdx.x; b < NBUCK_U; b += 256)
        hist_u[b * NBLK + blockIdx.x] = h[b];
    for (int b = threadIdx.x; b < NBUCK_I; b += 256)
        hist_i[b * NBLK + blockIdx.x] = h[NBUCK_U + b];
}

// One block per bucket: exclusive scan over its NBLK counts (RELATIVE,
// bucket-local) + emit the bucket total for the cross-bucket scan.
// offs layout [blk * nbuck + bucket] so msplit_scatter's loads coalesce.
__global__ __launch_bounds__(256) void msplit_offsets(
    const int* __restrict__ hist_u, const int* __restrict__ hist_i,
    int* __restrict__ offs_u, int* __restrict__ offs_i,
    int* __restrict__ tot_u, int* __restrict__ tot_i)
{
    __shared__ int buf[256];
    int b = blockIdx.x;
    const int* hist; int* offs; int* tot; int nbuck;
    if (b < NBUCK_U) { hist = hist_u; offs = offs_u; tot = tot_u; nbuck = NBUCK_U; }
    else { b -= NBUCK_U; hist = hist_i; offs = offs_i; tot = tot_i; nbuck = NBUCK_I; }
    const int t = threadIdx.x;
    const int x = (t < NBLK) ? hist[b * NBLK + t] : 0;
    buf[t] = x;
    __syncthreads();
    for (int d = 1; d < 256; d <<= 1) {
        const int y = (t >= d) ? buf[t - d] : 0;
        __syncthreads();
        buf[t] += y;
        __syncthreads();
    }
    if (t < NBLK) offs[t * nbuck + b] = buf[t] - x;   // bucket-relative
    if (t == 255) tot[b] = buf[255];                  // bucket total
}

// Cross-bucket exclusive scan (587 values total; block 0 = users, 1 = items).
// bbase[nb] = grand total (== NNZ) so bucket spans are [bbase[b], bbase[b+1]).
__global__ __launch_bounds__(512) void scan_buckets(
    const int* __restrict__ tot_u, int* __restrict__ bbase_u,
    const int* __restrict__ tot_i, int* __restrict__ bbase_i)
{
    __shared__ int buf[512];
    const int t = threadIdx.x;
    const int* tot; int* bbase; int nb;
    if (blockIdx.x == 0) { tot = tot_u; bbase = bbase_u; nb = NBUCK_U; }
    else                 { tot = tot_i; bbase = bbase_i; nb = NBUCK_I; }
    const int v = (t < nb) ? tot[t] : 0;
    buf[t] = v;
    __syncthreads();
    for (int d = 1; d < 512; d <<= 1) {
        const int y = (t >= d) ? buf[t - d] : 0;
        __syncthreads();
        buf[t] += y;
        __syncthreads();
    }
    if (t <= nb) bbase[t] = buf[t] - v;   // exclusive; bbase[nb] = total
}

// Scatter with LDS cursors: writes land in bucket-contiguous runs.
// u pack: col(16b) | local_row(8b)<<16 ; i pack: row(17b) | local_col(8b)<<17.
__global__ __launch_bounds__(256) void msplit_scatter(
    const int* __restrict__ rows, const int* __restrict__ cols,
    const float* __restrict__ vals,
    const int* __restrict__ offs_u, const int* __restrict__ offs_i,
    const int* __restrict__ bbase_u, const int* __restrict__ bbase_i,
    int2* __restrict__ stage_u, int2* __restrict__ stage_i)
{
    __shared__ int cu[NBUCK_U];
    __shared__ int ci[NBUCK_I];
    const int t = threadIdx.x;
    for (int b = t; b < NBUCK_U; b += 256)
        cu[b] = offs_u[blockIdx.x * NBUCK_U + b] + bbase_u[b];
    for (int b = t; b < NBUCK_I; b += 256)
        ci[b] = offs_i[blockIdx.x * NBUCK_I + b] + bbase_i[b];
    __syncthreads();
    const int base = blockIdx.x * EPB;
    const int end = min(base + EPB, NNZ_COUNT);
    for (int e = base + t; e < end; e += 256) {
        const int r = rows[e];
        const int c = cols[e];
        const int vb = __float_as_int(vals[e]);
        const int su = atomicAdd(&cu[r >> 8], 1);
        stage_u[su] = make_int2(c | ((r & 255) << 16), vb);
        const int si = atomicAdd(&ci[c >> 8], 1);
        stage_i[si] = make_int2(r | ((c & 255) << 17), vb);
    }
}

// Phase B (NEW): one block per bucket. Pass 1 LDS-histograms the bucket's
// 256 local rows (span is L2-resident, ~40-80KB), LDS-scans to produce the
// per-row CSR pointers (written to ptr[] inline — this replaces histo_kernel
// + the entire 3-kernel global scan), then scatters with LDS cursors.
__global__ __launch_bounds__(256) void bucket_build(
    const int* __restrict__ bbase_u, const int2* __restrict__ stage_u,
    int2* __restrict__ pairs_u, int* __restrict__ ptr_u,
    const int* __restrict__ bbase_i, const int2* __restrict__ stage_i,
    int2* __restrict__ pairs_i, int* __restrict__ ptr_i)
{
    __shared__ int hcnt[256];
    __shared__ int buf[256];
    __shared__ int cur[256];
    const int t = threadIdx.x;
    int b = blockIdx.x;
    const bool uside = (b < NBUCK_U);
    const int* bbase; const int2* stage; int2* pairs; int* ptr; int n; int sh;
    if (uside) { bbase = bbase_u; stage = stage_u; pairs = pairs_u; ptr = ptr_u; n = NUM_USERS; sh = 16; }
    else { b -= NBUCK_U; bbase = bbase_i; stage = stage_i; pairs = pairs_i; ptr = ptr_i; n = NUM_ITEMS; sh = 17; }
    const int beg = bbase[b];
    const int end = bbase[b + 1];

    hcnt[t] = 0;
    __syncthreads();
    for (int idx = beg + t; idx < end; idx += 256)
        atomicAdd(&hcnt[(stage[idx].x >> sh) & 255], 1);
    __syncthreads();

    const int v = hcnt[t];
    buf[t] = v;
    __syncthreads();
    for (int d = 1; d < 256; d <<= 1) {
        const int y = (t >= d) ? buf[t - d] : 0;
        __syncthreads();
        buf[t] += y;
        __syncthreads();
    }
    const int rowbase = beg + buf[t] - v;   // exclusive scan + bucket base
    cur[t] = rowbase;
    const int first = b << 8;
    if (first + t < n) ptr[first + t] = rowbase;
    if (first + t == n) ptr[n] = end;                       // partial last bucket
    else if (first + 256 == n && t == 0) ptr[n] = end;      // exact-fit last bucket
    __syncthreads();

    for (int idx = beg + t; idx < end; idx += 256) {
        const int2 s = stage[idx];
        const int local   = (s.x >> sh) & 255;
        const int payload = uside ? (s.x & 0xFFFF) : (s.x & 0x1FFFF);
        const int slot = atomicAdd(&cur[local], 1);
        pairs[slot] = make_int2(payload, s.y);
    }
}

// ---------------- SpMM: one 64-lane wave per destination row ----------------

template<bool WRITE_DST, bool HAS_BASE>
__device__ __forceinline__ void spmm_row_bf(
    const int* __restrict__ ptr, const int2* __restrict__ pairs,
    const unsigned* __restrict__ src, unsigned* __restrict__ dst,
    float* __restrict__ sum, const float* __restrict__ base,
    int row, int lane, float scale)
{
    const int start = ptr[row];
    const int end   = ptr[row + 1];
    float2 acc = make_float2(0.f, 0.f);

    for (int chunk = start; chunk < end; chunk += 64) {
        const int idx = chunk + lane;
        int2 p = make_int2(0, 0);
        if (idx < end) p = pairs[idx];
        int m = end - chunk; if (m > 64) m = 64;

        int j = 0;
        for (; j + 4 <= m; j += 4) {
            const int   c0 = __shfl(p.x, j),     c1 = __shfl(p.x, j + 1);
            const int   c2 = __shfl(p.x, j + 2), c3 = __shfl(p.x, j + 3);
            const float v0 = __int_as_float(__shfl(p.y, j));
            const float v1 = __int_as_float(__shfl(p.y, j + 1));
            const float v2 = __int_as_float(__shfl(p.y, j + 2));
            const float v3 = __int_as_float(__shfl(p.y, j + 3));
            const unsigned g0 = src[(size_t)c0 * 64 + lane];
            const unsigned g1 = src[(size_t)c1 * 64 + lane];
            const unsigned g2 = src[(size_t)c2 * 64 + lane];
            const unsigned g3 = src[(size_t)c3 * 64 + lane];
            acc.x += v0 * __uint_as_float(g0 << 16);
            acc.y += v0 * __uint_as_float(g0 & 0xFFFF0000u);
            acc.x += v1 * __uint_as_float(g1 << 16);
            acc.y += v1 * __uint_as_float(g1 & 0xFFFF0000u);
            acc.x += v2 * __uint_as_float(g2 << 16);
            acc.y += v2 * __uint_as_float(g2 & 0xFFFF0000u);
            acc.x += v3 * __uint_as_float(g3 << 16);
            acc.y += v3 * __uint_as_float(g3 & 0xFFFF0000u);
        }
        for (; j < m; ++j) {
            const int   c = __shfl(p.x, j);
            const float v = __int_as_float(__shfl(p.y, j));
            const unsigned g = src[(size_t)c * 64 + lane];
            acc.x += v * __uint_as_float(g << 16);
            acc.y += v * __uint_as_float(g & 0xFFFF0000u);
        }
    }

    if (WRITE_DST) dst[(size_t)row * 64 + lane] = pack_bf16(acc.x, acc.y);

    const size_t o = (size_t)row * EMBED_DIM + (lane << 1);
    float2 bsv;
    if (HAS_BASE) bsv = *reinterpret_cast<const float2*>(base + o);
    else          bsv = *reinterpret_cast<const float2*>(sum + o);
    bsv.x = (bsv.x + acc.x) * scale;
    bsv.y = (bsv.y + acc.y) * scale;
    *reinterpret_cast<float2*>(sum + o) = bsv;
}

template<bool WRITE_DST, bool HAS_BASE>
__global__ __launch_bounds__(256) void csr_spmm_dual_bf(
    const int*  __restrict__ ptr_u, const int2* __restrict__ pairs_u,
    const unsigned* __restrict__ src_u, unsigned* __restrict__ dst_u,
    float* __restrict__ sum_u, const float* __restrict__ base_u,
    const int*  __restrict__ ptr_i, const int2* __restrict__ pairs_i,
    const unsigned* __restrict__ src_i, unsigned* __restrict__ dst_i,
    float* __restrict__ sum_i, const float* __restrict__ base_i,
    int GU, float scale)
{
    const int lane = threadIdx.x & 63;
    const int w = threadIdx.x >> 6;
    if ((int)blockIdx.x < GU) {
        const int row = blockIdx.x * 4 + w;
        if (row < NUM_USERS)
            spmm_row_bf<WRITE_DST, HAS_BASE>(ptr_u, pairs_u, src_u, dst_u, sum_u, base_u, row, lane, scale);
    } else {
        const int row = ((int)blockIdx.x - GU) * 4 + w;
        if (row < NUM_ITEMS)
            spmm_row_bf<WRITE_DST, HAS_BASE>(ptr_i, pairs_i, src_i, dst_i, sum_i, base_i, row, lane, scale);
    }
}

// ---------------- fallback (round-1 atomic path) ----------------

__global__ __launch_bounds__(256) void edge_spmm(
    const float* __restrict__ vals, const int* __restrict__ rows,
    const int* __restrict__ cols, const float* __restrict__ u_src,
    const float* __restrict__ i_src, float* __restrict__ u_dst,
    float* __restrict__ i_dst, int nnz)
{
    const int lane = threadIdx.x & 31;
    const int e = blockIdx.x * 8 + (threadIdx.x >> 5);
    if (e >= nnz) return;
    const float v = vals[e];
    const size_t ro = (size_t)rows[e] * EMBED_DIM + lane * 4;
    const size_t co = (size_t)cols[e] * EMBED_DIM + lane * 4;
    const float4 iv = *reinterpret_cast<const float4*>(i_src + co);
    const float4 uv = *reinterpret_cast<const float4*>(u_src + ro);
    atomicAdd(u_dst + ro + 0, v * iv.x); atomicAdd(u_dst + ro + 1, v * iv.y);
    atomicAdd(u_dst + ro + 2, v * iv.z); atomicAdd(u_dst + ro + 3, v * iv.w);
    atomicAdd(i_dst + co + 0, v * uv.x); atomicAdd(i_dst + co + 1, v * uv.y);
    atomicAdd(i_dst + co + 2, v * uv.z); atomicAdd(i_dst + co + 3, v * uv.w);
}

__global__ __launch_bounds__(256) void acc_scale(
    float* __restrict__ out, const float* __restrict__ x, long n, float scale)
{
    long i = ((long)blockIdx.x * blockDim.x + threadIdx.x) * 4;
    if (i >= n) return;
    float4 o = *reinterpret_cast<float4*>(out + i);
    float4 a = *reinterpret_cast<const float4*>(x + i);
    o.x = (o.x + a.x) * scale; o.y = (o.y + a.y) * scale;
    o.z = (o.z + a.z) * scale; o.w = (o.w + a.w) * scale;
    *reinterpret_cast<float4*>(out + i) = o;
}

// ---------------- launch ----------------

extern "C" void kernel_launch(void* const* d_in, const int* in_sizes, int n_in,
                              void* d_out, int out_size, void* d_ws, size_t ws_size,
                              hipStream_t stream)
{
    const float* user = (const float*)d_in[0];
    const float* item = (const float*)d_in[1];
    const float* vals = (const float*)d_in[2];
    const int*   rows = (const int*)d_in[3];
    const int*   cols = (const int*)d_in[4];

    const size_t UD = (size_t)NUM_USERS * EMBED_DIM;   // 12.8M
    const size_t ID = (size_t)NUM_ITEMS * EMBED_DIM;   //  6.4M

    float* out_u = (float*)d_out;
    float* out_i = out_u + UD;

    // ---- CSR-path workspace layout ----
    char* ws = (char*)d_ws;
    unsigned* user_bf = (unsigned*)ws;              ws += UD * 2;
    unsigned* item_bf = (unsigned*)ws;              ws += ID * 2;
    unsigned* uA = (unsigned*)ws;                   ws += UD * 2;
    unsigned* uB = (unsigned*)ws;                   ws += UD * 2;
    unsigned* iA = (unsigned*)ws;                   ws += ID * 2;
    unsigned* iB = (unsigned*)ws;                   ws += ID * 2;
    int2* pairs_u = (int2*)ws;                      ws += (size_t)NNZ_COUNT * 8;
    int2* pairs_i = (int2*)ws;                      ws += (size_t)NNZ_COUNT * 8;
    int2* stage_u = (int2*)ws;                      ws += (size_t)NNZ_COUNT * 8;
    int2* stage_i = (int2*)ws;                      ws += (size_t)NNZ_COUNT * 8;
    int* ptr_u = (int*)ws;                          ws += (NUM_USERS + 1) * 4;
    int* ptr_i = (int*)ws;                          ws += (NUM_ITEMS + 1) * 4;
    int* bbase_u = (int*)ws;                        ws += (NBUCK_U + 1) * 4;
    int* bbase_i = (int*)ws;                        ws += (NBUCK_I + 1) * 4;
    const size_t REQ = (size_t)(ws - (char*)d_ws);  // ~180 MB (< R4's proven fit)

    // hist/offs/tot (~1.16 MB) alias into pairs_u: all consumed by
    // msplit_offsets/scan_buckets/msplit_scatter before bucket_build ever
    // writes pairs_u (disjoint lifetimes). bbase is NOT aliased: bucket_build
    // reads it while writing pairs_u.
    int* hist_u = (int*)pairs_u;
    int* hist_i = hist_u + NBUCK_U * NBLK;
    int* offs_u = hist_i + NBUCK_I * NBLK;
    int* offs_i = offs_u + NBLK * NBUCK_U;
    int* tot_u  = offs_i + NBLK * NBUCK_I;
    int* tot_i  = tot_u + NBUCK_U;

    if (ws_size >= REQ) {
        // ---- prep: bf16 copies of the input tables ----
        to_bf16_kernel<<<(int)(UD / 8 / 256), 256, 0, stream>>>(user, user_bf, (int)(UD / 8));
        to_bf16_kernel<<<(int)(ID / 8 / 256), 256, 0, stream>>>(item, item_bf, (int)(ID / 8));

        // ---- atomic-free CSR build ----
        msplit_hist<<<NBLK, 256, 0, stream>>>(rows, cols, hist_u, hist_i);
        msplit_offsets<<<NBUCK_U + NBUCK_I, 256, 0, stream>>>(
            hist_u, hist_i, offs_u, offs_i, tot_u, tot_i);
        scan_buckets<<<2, 512, 0, stream>>>(tot_u, bbase_u, tot_i, bbase_i);
        msplit_scatter<<<NBLK, 256, 0, stream>>>(
            rows, cols, vals, offs_u, offs_i, bbase_u, bbase_i, stage_u, stage_i);
        bucket_build<<<NBUCK_U + NBUCK_I, 256, 0, stream>>>(
            bbase_u, stage_u, pairs_u, ptr_u,
            bbase_i, stage_i, pairs_i, ptr_i);

        const int GU = (NUM_USERS + 3) / 4;   // 25000
        const int GI = (NUM_ITEMS + 3) / 4;   // 12500

        // layer 1: src = bf16 inputs; sum initialized from fp32 base (fused copy)
        csr_spmm_dual_bf<true, true><<<GU + GI, 256, 0, stream>>>(
            ptr_u, pairs_u, item_bf, uA, out_u, user,
            ptr_i, pairs_i, user_bf, iA, out_i, item, GU, 1.0f);
        // layer 2
        csr_spmm_dual_bf<true, false><<<GU + GI, 256, 0, stream>>>(
            ptr_u, pairs_u, iA, uB, out_u, nullptr,
            ptr_i, pairs_i, uA, iB, out_i, nullptr, GU, 1.0f);
        // layer 3: no dst store needed; fold final /4
        csr_spmm_dual_bf<false, false><<<GU + GI, 256, 0, stream>>>(
            ptr_u, pairs_u, iB, uA, out_u, nullptr,
            ptr_i, pairs_i, uB, iA, out_i, nullptr, GU, 0.25f);
    } else {
        // ---- fallback: round-1 atomic path (fp32 buffers carved from ws) ----
        char* fw = (char*)d_ws;
        float* fuA = (float*)fw;                    fw += UD * 4;
        float* fuB = (float*)fw;                    fw += UD * 4;
        float* fiA = (float*)fw;                    fw += ID * 4;
        float* fiB = (float*)fw;                    fw += ID * 4;

        const int EDGE_BLOCKS = (NNZ_COUNT + 7) / 8;
        const int ACC_U = (int)(UD / 1024), ACC_I = (int)(ID / 1024);

        hipMemcpyAsync(out_u, user, UD * 4, hipMemcpyDeviceToDevice, stream);
        hipMemcpyAsync(out_i, item, ID * 4, hipMemcpyDeviceToDevice, stream);

        hipMemsetAsync(fuA, 0, UD * 4, stream);
        hipMemsetAsync(fiA, 0, ID * 4, stream);
        edge_spmm<<<EDGE_BLOCKS, 256, 0, stream>>>(vals, rows, cols, user, item, fuA, fiA, NNZ_COUNT);
        acc_scale<<<ACC_U, 256, 0, stream>>>(out_u, fuA, (long)UD, 1.0f);
        acc_scale<<<ACC_I, 256, 0, stream>>>(out_i, fiA, (long)ID, 1.0f);

        hipMemsetAsync(fuB, 0, UD * 4, stream);
        hipMemsetAsync(fiB, 0, ID * 4, stream);
        edge_spmm<<<EDGE_BLOCKS, 256, 0, stream>>>(vals, rows, cols, fuA, fiA, fuB, fiB, NNZ_COUNT);
        acc_scale<<<ACC_U, 256, 0, stream>>>(out_u, fuB, (long)UD, 1.0f);
        acc_scale<<<ACC_I, 256, 0, stream>>>(out_i, fiB, (long)ID, 1.0f);

        hipMemsetAsync(fuA, 0, UD * 4, stream);
        hipMemsetAsync(fiA, 0, ID * 4, stream);
        edge_spmm<<<EDGE_BLOCKS, 256, 0, stream>>>(vals, rows, cols, fuB, fiB, fuA, fiA, NNZ_COUNT);
        acc_scale<<<ACC_U, 256, 0, stream>>>(out_u, fuA, (long)UD, 0.25f);
        acc_scale<<<ACC_I, 256, 0, stream>>>(out_i, fiA, (long)ID, 0.25f);
    }
}

// Round 2
// 657.719 us; speedup vs baseline: 1.3484x; 1.0707x over previous
//
#include <hip/hip_runtime.h>

// LightGCN-style 3-layer bipartite propagation.
// R7: SpMM layers were 3x155us with 458MB FETCH / 112MB WRITE each.
//  (a) Deferred sum: layers 1-2 no longer read/modify/write the fp32 running
//      sum (was 77+77 MB per dispatch); layer 3's epilogue computes
//      out = (base + l1 + l2 + acc)/4 from the persisted bf16 layer outputs.
//  (b) Packed 4B pairs: u = col(16b)|bf16(val)<<16, i = row(17b)|v15<<17
//      (val>=0 so sign bit dropped). Halves pairs traffic and per-edge
//      broadcast count.
//  (c) 8-wide gather unroll for deeper memory-level parallelism.
// Atomic-free multisplit CSR build (R6) kept. bf16 gather SpMM kept.

#define NUM_USERS 100000
#define NUM_ITEMS 50000
#define EMBED_DIM 128
#define NNZ_COUNT 2000000
#define NBUCK_U 391            // ceil(100000/256)
#define NBUCK_I 196            // ceil(50000/256)
#define EPB 8192               // edges per multisplit block
#define NBLK 245               // ceil(NNZ_COUNT/EPB)

// ---------------- bf16 helpers (manual RTNE) ----------------

__device__ __forceinline__ unsigned bf16_rnd(float f) {
    unsigned u = __float_as_uint(f);
    return (u + 0x7FFFu + ((u >> 16) & 1u)) >> 16;
}
__device__ __forceinline__ unsigned pack_bf16(float x, float y) {
    return bf16_rnd(x) | (bf16_rnd(y) << 16);
}

// Both embedding tables in one launch.
__global__ __launch_bounds__(256) void to_bf16_dual(
    const float* __restrict__ a, unsigned* __restrict__ oa, int na8,
    const float* __restrict__ b, unsigned* __restrict__ ob, int nb8)
{
    int i = blockIdx.x * 256 + threadIdx.x;
    const float4* s4; uint4* d4;
    if (i < na8) {
        s4 = reinterpret_cast<const float4*>(a) + i * 2;
        d4 = reinterpret_cast<uint4*>(oa) + i;
    } else {
        i -= na8;
        if (i >= nb8) return;
        s4 = reinterpret_cast<const float4*>(b) + i * 2;
        d4 = reinterpret_cast<uint4*>(ob) + i;
    }
    float4 x = s4[0], y = s4[1];
    uint4 r;
    r.x = pack_bf16(x.x, x.y); r.y = pack_bf16(x.z, x.w);
    r.z = pack_bf16(y.x, y.y); r.w = pack_bf16(y.z, y.w);
    *d4 = r;
}

// ---------------- LDS-aggregated multisplit (phase A) ----------------

__global__ __launch_bounds__(256) void msplit_hist(
    const int* __restrict__ rows, const int* __restrict__ cols,
    int* __restrict__ hist_u, int* __restrict__ hist_i)
{
    __shared__ int h[NBUCK_U + NBUCK_I];
    for (int i = threadIdx.x; i < NBUCK_U + NBUCK_I; i += 256) h[i] = 0;
    __syncthreads();
    const int base = blockIdx.x * EPB;
    const int end = min(base + EPB, NNZ_COUNT);
    for (int e = base + threadIdx.x; e < end; e += 256) {
        atomicAdd(&h[rows[e] >> 8], 1);
        atomicAdd(&h[NBUCK_U + (cols[e] >> 8)], 1);
    }
    __syncthreads();
    for (int b = threadIdx.x; b < NBUCK_U; b += 256)
        hist_u[b * NBLK + blockIdx.x] = h[b];
    for (int b = threadIdx.x; b < NBUCK_I; b += 256)
        hist_i[b * NBLK + blockIdx.x] = h[NBUCK_U + b];
}

// One block per bucket: exclusive scan over its NBLK counts (bucket-relative)
// + emit the bucket total for the cross-bucket scan.
__global__ __launch_bounds__(256) void msplit_offsets(
    const int* __restrict__ hist_u, const int* __restrict__ hist_i,
    int* __restrict__ offs_u, int* __restrict__ offs_i,
    int* __restrict__ tot_u, int* __restrict__ tot_i)
{
    __shared__ int buf[256];
    int b = blockIdx.x;
    const int* hist; int* offs; int* tot; int nbuck;
    if (b < NBUCK_U) { hist = hist_u; offs = offs_u; tot = tot_u; nbuck = NBUCK_U; }
    else { b -= NBUCK_U; hist = hist_i; offs = offs_i; tot = tot_i; nbuck = NBUCK_I; }
    const int t = threadIdx.x;
    const int x = (t < NBLK) ? hist[b * NBLK + t] : 0;
    buf[t] = x;
    __syncthreads();
    for (int d = 1; d < 256; d <<= 1) {
        const int y = (t >= d) ? buf[t - d] : 0;
        __syncthreads();
        buf[t] += y;
        __syncthreads();
    }
    if (t < NBLK) offs[t * nbuck + b] = buf[t] - x;   // bucket-relative
    if (t == 255) tot[b] = buf[255];                  // bucket total
}

// Cross-bucket exclusive scan (block 0 = users, 1 = items).
__global__ __launch_bounds__(512) void scan_buckets(
    const int* __restrict__ tot_u, int* __restrict__ bbase_u,
    const int* __restrict__ tot_i, int* __restrict__ bbase_i)
{
    __shared__ int buf[512];
    const int t = threadIdx.x;
    const int* tot; int* bbase; int nb;
    if (blockIdx.x == 0) { tot = tot_u; bbase = bbase_u; nb = NBUCK_U; }
    else                 { tot = tot_i; bbase = bbase_i; nb = NBUCK_I; }
    const int v = (t < nb) ? tot[t] : 0;
    buf[t] = v;
    __syncthreads();
    for (int d = 1; d < 512; d <<= 1) {
        const int y = (t >= d) ? buf[t - d] : 0;
        __syncthreads();
        buf[t] += y;
        __syncthreads();
    }
    if (t <= nb) bbase[t] = buf[t] - v;   // exclusive; bbase[nb] = total
}

// Scatter with LDS cursors: writes land in bucket-contiguous runs.
// u stage: col(16b) | local_row(8b)<<16 ; i stage: row(17b) | local_col(8b)<<17.
__global__ __launch_bounds__(256) void msplit_scatter(
    const int* __restrict__ rows, const int* __restrict__ cols,
    const float* __restrict__ vals,
    const int* __restrict__ offs_u, const int* __restrict__ offs_i,
    const int* __restrict__ bbase_u, const int* __restrict__ bbase_i,
    int2* __restrict__ stage_u, int2* __restrict__ stage_i)
{
    __shared__ int cu[NBUCK_U];
    __shared__ int ci[NBUCK_I];
    const int t = threadIdx.x;
    for (int b = t; b < NBUCK_U; b += 256)
        cu[b] = offs_u[blockIdx.x * NBUCK_U + b] + bbase_u[b];
    for (int b = t; b < NBUCK_I; b += 256)
        ci[b] = offs_i[blockIdx.x * NBUCK_I + b] + bbase_i[b];
    __syncthreads();
    const int base = blockIdx.x * EPB;
    const int end = min(base + EPB, NNZ_COUNT);
    for (int e = base + t; e < end; e += 256) {
        const int r = rows[e];
        const int c = cols[e];
        const int vb = __float_as_int(vals[e]);
        const int su = atomicAdd(&cu[r >> 8], 1);
        stage_u[su] = make_int2(c | ((r & 255) << 16), vb);
        const int si = atomicAdd(&ci[c >> 8], 1);
        stage_i[si] = make_int2(r | ((c & 255) << 17), vb);
    }
}

// Phase B: one block per bucket. LDS histogram of the bucket's 256 local
// rows -> LDS scan -> per-row CSR pointers written inline -> LDS-cursor
// scatter into packed 4B pairs:
//   u pair: col(16b) | bf16(val)<<16
//   i pair: row(17b) | (bf16(val)&0x7FFF)<<17   (val >= 0, sign dropped)
__global__ __launch_bounds__(256) void bucket_build(
    const int* __restrict__ bbase_u, const int2* __restrict__ stage_u,
    unsigned* __restrict__ pairs_u, int* __restrict__ ptr_u,
    const int* __restrict__ bbase_i, const int2* __restrict__ stage_i,
    unsigned* __restrict__ pairs_i, int* __restrict__ ptr_i)
{
    __shared__ int hcnt[256];
    __shared__ int buf[256];
    __shared__ int cur[256];
    const int t = threadIdx.x;
    int b = blockIdx.x;
    const bool uside = (b < NBUCK_U);
    const int* bbase; const int2* stage; unsigned* pairs; int* ptr; int n; int sh;
    if (uside) { bbase = bbase_u; stage = stage_u; pairs = pairs_u; ptr = ptr_u; n = NUM_USERS; sh = 16; }
    else { b -= NBUCK_U; bbase = bbase_i; stage = stage_i; pairs = pairs_i; ptr = ptr_i; n = NUM_ITEMS; sh = 17; }
    const int beg = bbase[b];
    const int end = bbase[b + 1];

    hcnt[t] = 0;
    __syncthreads();
    for (int idx = beg + t; idx < end; idx += 256)
        atomicAdd(&hcnt[(stage[idx].x >> sh) & 255], 1);
    __syncthreads();

    const int v = hcnt[t];
    buf[t] = v;
    __syncthreads();
    for (int d = 1; d < 256; d <<= 1) {
        const int y = (t >= d) ? buf[t - d] : 0;
        __syncthreads();
        buf[t] += y;
        __syncthreads();
    }
    const int rowbase = beg + buf[t] - v;   // exclusive scan + bucket base
    cur[t] = rowbase;
    const int first = b << 8;
    if (first + t < n) ptr[first + t] = rowbase;
    if (first + t == n) ptr[n] = end;                       // partial last bucket
    else if (first + 256 == n && t == 0) ptr[n] = end;      // exact-fit last bucket
    __syncthreads();

    for (int idx = beg + t; idx < end; idx += 256) {
        const int2 s = stage[idx];
        const int local = (s.x >> sh) & 255;
        const unsigned vb = bf16_rnd(__int_as_float(s.y));
        unsigned packed;
        if (uside) packed = (unsigned)(s.x & 0xFFFF) | (vb << 16);
        else       packed = (unsigned)(s.x & 0x1FFFF) | ((vb & 0x7FFFu) << 17);
        const int slot = atomicAdd(&cur[local], 1);
        pairs[slot] = packed;
    }
}

// ---------------- SpMM: one 64-lane wave per destination row ----------------

template<bool USIDE>
__device__ __forceinline__ void decode_pair(unsigned s, int& c, float& v) {
    if (USIDE) { c = (int)(s & 0xFFFFu);  v = __uint_as_float(s & 0xFFFF0000u); }
    else       { c = (int)(s & 0x1FFFFu); v = __uint_as_float((s & 0xFFFE0000u) >> 1); }
}

// MODE 0: write bf16 dst only (no sum traffic).
// MODE 1: final layer — out = (base + l1 + l2 + acc) * 0.25, no dst store.
template<int MODE, bool USIDE>
__device__ __forceinline__ void spmm_row_bf(
    const int* __restrict__ ptr, const unsigned* __restrict__ pairs,
    const unsigned* __restrict__ src, unsigned* __restrict__ dst,
    const unsigned* __restrict__ l1, const unsigned* __restrict__ l2,
    const float* __restrict__ base, float* __restrict__ out,
    int row, int lane)
{
    const int start = ptr[row];
    const int end   = ptr[row + 1];
    float2 acc = make_float2(0.f, 0.f);

    for (int chunk = start; chunk < end; chunk += 64) {
        const int idx = chunk + lane;
        const unsigned p = (idx < end) ? pairs[idx] : 0u;
        int m = end - chunk; if (m > 64) m = 64;

        int j = 0;
        for (; j + 8 <= m; j += 8) {
            unsigned sv[8]; int c[8]; float v[8]; unsigned g[8];
            #pragma unroll
            for (int k = 0; k < 8; ++k) sv[k] = (unsigned)__shfl((int)p, j + k);
            #pragma unroll
            for (int k = 0; k < 8; ++k) {
                decode_pair<USIDE>(sv[k], c[k], v[k]);
                g[k] = src[(size_t)c[k] * 64 + lane];
            }
            #pragma unroll
            for (int k = 0; k < 8; ++k) {
                acc.x += v[k] * __uint_as_float(g[k] << 16);
                acc.y += v[k] * __uint_as_float(g[k] & 0xFFFF0000u);
            }
        }
        for (; j < m; ++j) {
            const unsigned s = (unsigned)__shfl((int)p, j);
            int c; float v;
            decode_pair<USIDE>(s, c, v);
            const unsigned g = src[(size_t)c * 64 + lane];
            acc.x += v * __uint_as_float(g << 16);
            acc.y += v * __uint_as_float(g & 0xFFFF0000u);
        }
    }

    if (MODE == 0) {
        dst[(size_t)row * 64 + lane] = pack_bf16(acc.x, acc.y);
    } else {
        const unsigned a1 = l1[(size_t)row * 64 + lane];
        const unsigned a2 = l2[(size_t)row * 64 + lane];
        const size_t o = (size_t)row * EMBED_DIM + (lane << 1);
        const float2 bs = *reinterpret_cast<const float2*>(base + o);
        float2 r;
        r.x = (bs.x + __uint_as_float(a1 << 16) + __uint_as_float(a2 << 16) + acc.x) * 0.25f;
        r.y = (bs.y + __uint_as_float(a1 & 0xFFFF0000u) + __uint_as_float(a2 & 0xFFFF0000u) + acc.y) * 0.25f;
        *reinterpret_cast<float2*>(out + o) = r;
    }
}

template<int MODE>
__global__ __launch_bounds__(256) void csr_spmm_dual_bf(
    const int* __restrict__ ptr_u, const unsigned* __restrict__ pairs_u,
    const unsigned* __restrict__ src_u, unsigned* __restrict__ dst_u,
    const unsigned* __restrict__ l1_u, const unsigned* __restrict__ l2_u,
    const float* __restrict__ base_u, float* __restrict__ out_u,
    const int* __restrict__ ptr_i, const unsigned* __restrict__ pairs_i,
    const unsigned* __restrict__ src_i, unsigned* __restrict__ dst_i,
    const unsigned* __restrict__ l1_i, const unsigned* __restrict__ l2_i,
    const float* __restrict__ base_i, float* __restrict__ out_i,
    int GU)
{
    const int lane = threadIdx.x & 63;
    const int w = threadIdx.x >> 6;
    if ((int)blockIdx.x < GU) {
        const int row = blockIdx.x * 4 + w;
        if (row < NUM_USERS)
            spmm_row_bf<MODE, true>(ptr_u, pairs_u, src_u, dst_u, l1_u, l2_u, base_u, out_u, row, lane);
    } else {
        const int row = ((int)blockIdx.x - GU) * 4 + w;
        if (row < NUM_ITEMS)
            spmm_row_bf<MODE, false>(ptr_i, pairs_i, src_i, dst_i, l1_i, l2_i, base_i, out_i, row, lane);
    }
}

// ---------------- fallback (round-1 atomic path) ----------------

__global__ __launch_bounds__(256) void edge_spmm(
    const float* __restrict__ vals, const int* __restrict__ rows,
    const int* __restrict__ cols, const float* __restrict__ u_src,
    const float* __restrict__ i_src, float* __restrict__ u_dst,
    float* __restrict__ i_dst, int nnz)
{
    const int lane = threadIdx.x & 31;
    const int e = blockIdx.x * 8 + (threadIdx.x >> 5);
    if (e >= nnz) return;
    const float v = vals[e];
    const size_t ro = (size_t)rows[e] * EMBED_DIM + lane * 4;
    const size_t co = (size_t)cols[e] * EMBED_DIM + lane * 4;
    const float4 iv = *reinterpret_cast<const float4*>(i_src + co);
    const float4 uv = *reinterpret_cast<const float4*>(u_src + ro);
    atomicAdd(u_dst + ro + 0, v * iv.x); atomicAdd(u_dst + ro + 1, v * iv.y);
    atomicAdd(u_dst + ro + 2, v * iv.z); atomicAdd(u_dst + ro + 3, v * iv.w);
    atomicAdd(i_dst + co + 0, v * uv.x); atomicAdd(i_dst + co + 1, v * uv.y);
    atomicAdd(i_dst + co + 2, v * uv.z); atomicAdd(i_dst + co + 3, v * uv.w);
}

__global__ __launch_bounds__(256) void acc_scale(
    float* __restrict__ out, const float* __restrict__ x, long n, float scale)
{
    long i = ((long)blockIdx.x * blockDim.x + threadIdx.x) * 4;
    if (i >= n) return;
    float4 o = *reinterpret_cast<float4*>(out + i);
    float4 a = *reinterpret_cast<const float4*>(x + i);
    o.x = (o.x + a.x) * scale; o.y = (o.y + a.y) * scale;
    o.z = (o.z + a.z) * scale; o.w = (o.w + a.w) * scale;
    *reinterpret_cast<float4*>(out + i) = o;
}

// ---------------- launch ----------------

extern "C" void kernel_launch(void* const* d_in, const int* in_sizes, int n_in,
                              void* d_out, int out_size, void* d_ws, size_t ws_size,
                              hipStream_t stream)
{
    const float* user = (const float*)d_in[0];
    const float* item = (const float*)d_in[1];
    const float* vals = (const float*)d_in[2];
    const int*   rows = (const int*)d_in[3];
    const int*   cols = (const int*)d_in[4];

    const size_t UD = (size_t)NUM_USERS * EMBED_DIM;   // 12.8M
    const size_t ID = (size_t)NUM_ITEMS * EMBED_DIM;   //  6.4M

    float* out_u = (float*)d_out;
    float* out_i = out_u + UD;

    // ---- CSR-path workspace layout ----
    char* ws = (char*)d_ws;
    unsigned* user_bf = (unsigned*)ws;              ws += UD * 2;
    unsigned* item_bf = (unsigned*)ws;              ws += ID * 2;
    unsigned* uA = (unsigned*)ws;                   ws += UD * 2;
    unsigned* uB = (unsigned*)ws;                   ws += UD * 2;
    unsigned* iA = (unsigned*)ws;                   ws += ID * 2;
    unsigned* iB = (unsigned*)ws;                   ws += ID * 2;
    unsigned* pairs_u = (unsigned*)ws;              ws += (size_t)NNZ_COUNT * 4;
    unsigned* pairs_i = (unsigned*)ws;              ws += (size_t)NNZ_COUNT * 4;
    int2* stage_u = (int2*)ws;                      ws += (size_t)NNZ_COUNT * 8;
    int2* stage_i = (int2*)ws;                      ws += (size_t)NNZ_COUNT * 8;
    int* ptr_u = (int*)ws;                          ws += (NUM_USERS + 1) * 4;
    int* ptr_i = (int*)ws;                          ws += (NUM_ITEMS + 1) * 4;
    int* bbase_u = (int*)ws;                        ws += (NBUCK_U + 1) * 4;
    int* bbase_i = (int*)ws;                        ws += (NBUCK_I + 1) * 4;
    const size_t REQ = (size_t)(ws - (char*)d_ws);  // ~164 MB

    // hist/offs/tot (~1.16 MB) alias into pairs_u: all consumed by
    // msplit_offsets/scan_buckets/msplit_scatter before bucket_build ever
    // writes pairs_u (disjoint lifetimes). bbase is NOT aliased.
    int* hist_u = (int*)pairs_u;
    int* hist_i = hist_u + NBUCK_U * NBLK;
    int* offs_u = hist_i + NBUCK_I * NBLK;
    int* offs_i = offs_u + NBLK * NBUCK_U;
    int* tot_u  = offs_i + NBLK * NBUCK_I;
    int* tot_i  = tot_u + NBUCK_U;

    if (ws_size >= REQ) {
        // ---- prep: bf16 copies of the input tables ----
        const int NA8 = (int)(UD / 8), NB8 = (int)(ID / 8);
        to_bf16_dual<<<(NA8 + NB8 + 255) / 256, 256, 0, stream>>>(
            user, user_bf, NA8, item, item_bf, NB8);

        // ---- atomic-free CSR build ----
        msplit_hist<<<NBLK, 256, 0, stream>>>(rows, cols, hist_u, hist_i);
        msplit_offsets<<<NBUCK_U + NBUCK_I, 256, 0, stream>>>(
            hist_u, hist_i, offs_u, offs_i, tot_u, tot_i);
        scan_buckets<<<2, 512, 0, stream>>>(tot_u, bbase_u, tot_i, bbase_i);
        msplit_scatter<<<NBLK, 256, 0, stream>>>(
            rows, cols, vals, offs_u, offs_i, bbase_u, bbase_i, stage_u, stage_i);
        bucket_build<<<NBUCK_U + NBUCK_I, 256, 0, stream>>>(
            bbase_u, stage_u, pairs_u, ptr_u,
            bbase_i, stage_i, pairs_i, ptr_i);

        const int GU = (NUM_USERS + 3) / 4;   // 25000
        const int GI = (NUM_ITEMS + 3) / 4;   // 12500

        // layer 1: src = bf16 inputs -> uA/iA (dst only, no sum traffic)
        csr_spmm_dual_bf<0><<<GU + GI, 256, 0, stream>>>(
            ptr_u, pairs_u, item_bf, uA, nullptr, nullptr, nullptr, nullptr,
            ptr_i, pairs_i, user_bf, iA, nullptr, nullptr, nullptr, nullptr, GU);
        // layer 2: src = uA/iA -> uB/iB
        csr_spmm_dual_bf<0><<<GU + GI, 256, 0, stream>>>(
            ptr_u, pairs_u, iA, uB, nullptr, nullptr, nullptr, nullptr,
            ptr_i, pairs_i, uA, iB, nullptr, nullptr, nullptr, nullptr, GU);
        // layer 3: fused epilogue out = (base + l1 + l2 + acc) / 4
        csr_spmm_dual_bf<1><<<GU + GI, 256, 0, stream>>>(
            ptr_u, pairs_u, iB, nullptr, uA, uB, user, out_u,
            ptr_i, pairs_i, uB, nullptr, iA, iB, item, out_i, GU);
    } else {
        // ---- fallback: round-1 atomic path (fp32 buffers carved from ws) ----
        char* fw = (char*)d_ws;
        float* fuA = (float*)fw;                    fw += UD * 4;
        float* fuB = (float*)fw;                    fw += UD * 4;
        float* fiA = (float*)fw;                    fw += ID * 4;
        float* fiB = (float*)fw;                    fw += ID * 4;

        const int EDGE_BLOCKS = (NNZ_COUNT + 7) / 8;
        const int ACC_U = (int)(UD / 1024), ACC_I = (int)(ID / 1024);

        hipMemcpyAsync(out_u, user, UD * 4, hipMemcpyDeviceToDevice, stream);
        hipMemcpyAsync(out_i, item, ID * 4, hipMemcpyDeviceToDevice, stream);

        hipMemsetAsync(fuA, 0, UD * 4, stream);
        hipMemsetAsync(fiA, 0, ID * 4, stream);
        edge_spmm<<<EDGE_BLOCKS, 256, 0, stream>>>(vals, rows, cols, user, item, fuA, fiA, NNZ_COUNT);
        acc_scale<<<ACC_U, 256, 0, stream>>>(out_u, fuA, (long)UD, 1.0f);
        acc_scale<<<ACC_I, 256, 0, stream>>>(out_i, fiA, (long)ID, 1.0f);

        hipMemsetAsync(fuB, 0, UD * 4, stream);
        hipMemsetAsync(fiB, 0, ID * 4, stream);
        edge_spmm<<<EDGE_BLOCKS, 256, 0, stream>>>(vals, rows, cols, fuA, fiA, fuB, fiB, NNZ_COUNT);
        acc_scale<<<ACC_U, 256, 0, stream>>>(out_u, fuB, (long)UD, 1.0f);
        acc_scale<<<ACC_I, 256, 0, stream>>>(out_i, fiB, (long)ID, 1.0f);

        hipMemsetAsync(fuA, 0, UD * 4, stream);
        hipMemsetAsync(fiA, 0, ID * 4, stream);
        edge_spmm<<<EDGE_BLOCKS, 256, 0, stream>>>(vals, rows, cols, fuB, fiB, fuA, fiA, NNZ_COUNT);
        acc_scale<<<ACC_U, 256, 0, stream>>>(out_u, fuA, (long)UD, 0.25f);
        acc_scale<<<ACC_I, 256, 0, stream>>>(out_i, fiA, (long)ID, 0.25f);
    }
}